// Round 23
// baseline (198.310 us; speedup 1.0000x reference)
//
#include <hip/hip_runtime.h>
#include <stdint.h>

using u16 = unsigned short;
typedef __attribute__((ext_vector_type(8))) _Float16 half8;
typedef __attribute__((ext_vector_type(4))) float f32x4;
typedef __attribute__((ext_vector_type(4))) unsigned short u16x4;

#define S_LEN 2048
#define D_MODEL 1024
#define NHEAD 16
#define HDIM 64

__device__ __forceinline__ u16 f2h_bits(float f){
    _Float16 h = (_Float16)f;
    return __builtin_bit_cast(u16, h);
}
__device__ __forceinline__ float h2f_bits(u16 v){
    return (float)__builtin_bit_cast(_Float16, v);
}

typedef __attribute__((address_space(1))) void gvoid;
typedef __attribute__((address_space(3))) void lvoid;
__device__ __forceinline__ void gload_lds16(const u16* g, u16* l){
    __builtin_amdgcn_global_load_lds((gvoid*)(uintptr_t)g, (lvoid*)l, 16, 0, 0);
}

// ---------- fused converts + flag clear ----------
// blocks 0..4095: x fp32->fp16; 4096..8191: weight transposes; 8192: zero merge flags
// (runs before k_attn on the same stream -> flags deterministically 0 every call).
__global__ __launch_bounds__(256) void k_cvt(const float* __restrict__ x, u16* __restrict__ xh,
                                             const float* __restrict__ W0, u16* __restrict__ T0,
                                             const float* __restrict__ W1, u16* __restrict__ T1,
                                             unsigned* __restrict__ flags){
    __shared__ float tt[32][33];
    int blk = blockIdx.x;
    if (blk >= 8192){
        if (threadIdx.x < 256) flags[threadIdx.x] = 0u;
        return;
    }
    if (blk < 4096){
        int i = blk*256 + threadIdx.x;
        float4 v = reinterpret_cast<const float4*>(x)[i];
        u16x4 o;
        o.x = f2h_bits(v.x); o.y = f2h_bits(v.y); o.z = f2h_bits(v.z); o.w = f2h_bits(v.w);
        reinterpret_cast<u16x4*>(xh)[i] = o;
        return;
    }
    int wi = blk - 4096;
    int bx = wi & 127, ky = wi >> 7;
    const float* W; u16* WT; int N, n0;
    if (bx < 96){ W = W0; WT = T0; N = 3072; n0 = bx*32; }
    else        { W = W1; WT = T1; N = 1024; n0 = (bx-96)*32; }
    int k0 = ky*32;
    int tx = threadIdx.x & 31, ty = threadIdx.x >> 5;
    #pragma unroll
    for (int i=0;i<4;++i) tt[ty+8*i][tx] = W[(size_t)(k0+ty+8*i)*N + n0+tx];
    __syncthreads();
    #pragma unroll
    for (int i=0;i<4;++i) WT[(size_t)(n0+ty+8*i)*1024 + k0+tx] = f2h_bits(tt[tx][ty+8*i]);
}

// ---------- GEMM: 128xBN block tile, BK=32, dbuf LDS, ONE barrier per K-step ----------
template<int EPI, int BN>
__global__ __launch_bounds__(256) void k_gemm(const u16* __restrict__ A, const u16* __restrict__ BT,
                                              float* __restrict__ Cf, u16* __restrict__ Qh,
                                              u16* __restrict__ Kh, u16* __restrict__ Vt){
    constexpr int Kd = 1024;
    constexpr int NF = BN/32;
    __shared__ u16 As[2*128*32];
    __shared__ u16 Bs[2*128*32];
    int nwg = gridDim.x;
    int cpx = nwg >> 3;
    int wg  = ((int)blockIdx.x & 7)*cpx + ((int)blockIdx.x >> 3);   // XCD-chunked
    int tm = wg & 31, tn = wg >> 5;
    int t = threadIdx.x;
    int w = t >> 6, lane = t & 63;
    int lr = lane & 15, lg = lane >> 4;
    int wm = (w>>1)*64, wn = (w&1)*(BN/2);
    int m0 = tm*128 + wm, n0 = tn*BN + wn;

    const u16* aG = A  + (size_t)(tm*128 + (t>>2))*Kd + (t&3)*8;
    const u16* bG = BT + (size_t)(tn*BN + (t>>2))*Kd + (t&3)*8;
    u16* aL = As + (t>>2)*32 + (t&3)*8;
    u16* bL = Bs + (t>>2)*32 + (t&3)*8;

    auto stage = [&](int buf, int kk){
        gload_lds16(aG + kk, aL + buf*4096);
        gload_lds16(aG + kk + (size_t)64*Kd, aL + buf*4096 + 64*32);
        gload_lds16(bG + kk, bL + buf*4096);
        if (BN == 128) gload_lds16(bG + kk + (size_t)64*Kd, bL + buf*4096 + 64*32);
    };

    f32x4 acc[4][NF];
    #pragma unroll
    for (int i=0;i<4;++i)
        #pragma unroll
        for (int j=0;j<NF;++j) acc[i][j] = (f32x4){0.f,0.f,0.f,0.f};

    stage(0, 0);
    __syncthreads();
    for (int kk=0; kk<Kd; kk+=32){
        int cur = (kk>>5) & 1;
        if (kk+32 < Kd) stage(cur^1, kk+32);

        half8 av[4], bv[NF];
        #pragma unroll
        for (int mf=0;mf<4;++mf) av[mf] = *reinterpret_cast<const half8*>(&As[cur*4096 + (wm+mf*16+lr)*32 + lg*8]);
        #pragma unroll
        for (int nf=0;nf<NF;++nf) bv[nf] = *reinterpret_cast<const half8*>(&Bs[cur*4096 + (wn+nf*16+lr)*32 + lg*8]);
        __builtin_amdgcn_s_setprio(1);
        #pragma unroll
        for (int mf=0;mf<4;++mf)
            #pragma unroll
            for (int nf=0;nf<NF;++nf)
                acc[mf][nf] = __builtin_amdgcn_mfma_f32_16x16x32_f16(av[mf], bv[nf], acc[mf][nf], 0,0,0);
        __builtin_amdgcn_s_setprio(0);
        __syncthreads();
    }

    if (EPI == 0){
        #pragma unroll
        for (int mf=0;mf<4;++mf)
            #pragma unroll
            for (int nf=0;nf<NF;++nf)
                #pragma unroll
                for (int j=0;j<4;++j)
                    Cf[(size_t)(m0+mf*16+lg*4+j)*D_MODEL + n0+nf*16+lr] = acc[mf][nf][j];
    } else {
        #pragma unroll
        for (int mf=0;mf<4;++mf){
            int r0 = m0 + mf*16 + lg*4;
            int b  = r0 >> 11, s = r0 & 2047;
            #pragma unroll
            for (int nf=0;nf<NF;++nf){
                int col = n0 + nf*16 + lr;
                int which = col >> 10;
                int d  = col & 1023;
                int h  = d >> 6, di = d & 63;
                int bh = b*NHEAD + h;
                if (which == 2){
                    u16x4 pv;
                    pv.x = f2h_bits(acc[mf][nf][0]);
                    pv.y = f2h_bits(acc[mf][nf][1]);
                    pv.z = f2h_bits(acc[mf][nf][2]);
                    pv.w = f2h_bits(acc[mf][nf][3]);
                    *reinterpret_cast<u16x4*>(Vt + ((size_t)bh*HDIM + di)*S_LEN + s) = pv;
                } else {
                    u16* dst = (which==0 ? Qh : Kh) + ((size_t)bh*S_LEN + s)*HDIM + di;
                    #pragma unroll
                    for (int j=0;j<4;++j) dst[(size_t)j*HDIM] = f2h_bits(acc[mf][nf][j]);
                }
            }
        }
    }
}

// ---------- flash attention: r22 body + second-finisher tail merge (k_comb deleted) ----------
// Split parts write normalized partials as before; then threadfence -> barrier ->
// thread0 atomicAdd(flag) (device-scope); the SECOND finisher re-reads both partials
// (fence-acquire) and does k_comb's exact merge inline. Saves one dispatch + its gap.
__global__ __launch_bounds__(256,3) void k_attn(const u16* __restrict__ Q, const u16* __restrict__ K,
                                                const u16* __restrict__ Vt, u16* __restrict__ Mg,
                                                u16* __restrict__ On, float* __restrict__ Ml,
                                                float* __restrict__ Ll, unsigned* __restrict__ flags){
    __shared__ u16 Kl[2*64*64];
    __shared__ u16 Vl[2*64*64];
    __shared__ u16 plds[4][32][72];
    __shared__ unsigned oldv;
    int t = threadIdx.x;
    int w = t >> 6, lane = t & 63;
    int lr = lane & 15, lg = lane >> 4;
    int blk = blockIdx.x;
    int bh  = blk & 31;                      // XCD = bh%8: K/V L2-pinned
    int p   = blk >> 5;                      // 0..23
    int qb, ktLo, ktHi; bool split;
    int part = 0;
    if (p < 8)      { qb = p;    ktLo = 0;      ktHi = 2*p+2;   split = false; }
    else if (p < 16){ qb = 23-p; ktLo = 0;      ktHi = qb+1;    split = true;  part = 0; }
    else            { qb = 31-p; ktLo = qb+1;   ktHi = 2*qb+2;  split = true;  part = 1; }
    (void)part;
    int q0w = qb*128 + w*32;
    int b = bh >> 4, h = bh & 15;
    int fidx = (bh<<3) + (qb-8);             // valid only when split
    int pid = split ? fidx*2 + part : 0;
    const u16* Qp = Q  + (size_t)bh*S_LEN*HDIM;
    const u16* Kp = K  + (size_t)bh*S_LEN*HDIM;
    const u16* Vp = Vt + (size_t)bh*HDIM*S_LEN;

    int c0 = t, c1 = t + 256;
    int r0 = c0 >> 3, s0 = 8*((c0 & 7) ^ (r0 & 7));
    int r1 = c1 >> 3, s1 = 8*((c1 & 7) ^ (r1 & 7));
    const u16* Ks0 = Kp + (size_t)r0*HDIM + s0;
    const u16* Ks1 = Kp + (size_t)r1*HDIM + s1;
    const u16* Vs0 = Vp + (size_t)r0*S_LEN + s0;
    const u16* Vs1 = Vp + (size_t)r1*S_LEN + s1;
    u16* Kd0 = Kl + c0*8; u16* Kd1 = Kl + c1*8;
    u16* Vd0 = Vl + c0*8; u16* Vd1 = Vl + c1*8;

    auto stageKV = [&](int buf, int kt){
        int kbase = kt*64;
        gload_lds16(Ks0 + (size_t)kbase*HDIM, Kd0 + buf*4096);
        gload_lds16(Ks1 + (size_t)kbase*HDIM, Kd1 + buf*4096);
        gload_lds16(Vs0 + kbase, Vd0 + buf*4096);
        gload_lds16(Vs1 + kbase, Vd1 + buf*4096);
    };

    half8 qf[2][2];
    #pragma unroll
    for (int qi=0;qi<2;++qi)
        #pragma unroll
        for (int ks=0;ks<2;++ks){
            half8 v = *reinterpret_cast<const half8*>(Qp + (size_t)(q0w+qi*16+lr)*HDIM + ks*32 + lg*8);
            #pragma unroll
            for (int j=0;j<8;++j) v[j] = v[j] * (_Float16)1.44269504f;
            qf[qi][ks] = v;
        }

    f32x4 oacc[2][4];
    float mrow[2], lrow[2];
    #pragma unroll
    for (int mf=0;mf<2;++mf){
        #pragma unroll
        for (int nf=0;nf<4;++nf) oacc[mf][nf] = (f32x4){0.f,0.f,0.f,0.f};
        mrow[mf] = -1e30f; lrow[mf] = 0.f;
    }

    int lastkt = (q0w + 31) >> 6;
    int swz = (lr & 7)*8;
    int nT = ktHi - ktLo;

    stageKV(0, ktLo);
    __syncthreads();
    for (int i=0; i<nT; ++i){
        int kt = ktLo + i;
        int cur = i & 1;
        if (i+1 < nT) stageKV(cur^1, kt+1);

        if (kt <= lastkt){
            const u16* Kb = Kl + cur*4096;
            const u16* Vb = Vl + cur*4096;
            int kbase = kt*64;
            half8 kfr[4][2];
            #pragma unroll
            for (int kf=0;kf<4;++kf)
                #pragma unroll
                for (int ks=0;ks<2;++ks)
                    kfr[kf][ks] = *reinterpret_cast<const half8*>(Kb + (kf*16+lr)*64 + ((ks*32 + lg*8) ^ swz));
            f32x4 sc[4][2];
            #pragma unroll
            for (int kf=0;kf<4;++kf)
                #pragma unroll
                for (int qi=0;qi<2;++qi) sc[kf][qi] = (f32x4){0.f,0.f,0.f,0.f};
            __builtin_amdgcn_s_setprio(1);
            #pragma unroll
            for (int kf=0;kf<4;++kf)
                #pragma unroll
                for (int qi=0;qi<2;++qi)
                    #pragma unroll
                    for (int ks=0;ks<2;++ks)
                        sc[kf][qi] = __builtin_amdgcn_mfma_f32_16x16x32_f16(kfr[kf][ks], qf[qi][ks], sc[kf][qi], 0,0,0);
            __builtin_amdgcn_s_setprio(0);

            half8 vf[4][2];
            #pragma unroll
            for (int nf=0;nf<4;++nf)
                #pragma unroll
                for (int kh=0;kh<2;++kh)
                    vf[nf][kh] = *reinterpret_cast<const half8*>(Vb + (nf*16+lr)*64 + ((kh*32 + lg*8) ^ swz));

            if (kt == lastkt){
                #pragma unroll
                for (int kf=0;kf<4;++kf)
                    #pragma unroll
                    for (int qi=0;qi<2;++qi)
                        #pragma unroll
                        for (int j=0;j<4;++j)
                            if (kbase+kf*16+lg*4+j > q0w+qi*16+lr) sc[kf][qi][j] = -1e9f;
            }

            float pmax[2];
            #pragma unroll
            for (int qi=0;qi<2;++qi){
                float t0 = fmaxf(fmaxf(sc[0][qi][0], sc[0][qi][1]), fmaxf(sc[0][qi][2], sc[0][qi][3]));
                float t1 = fmaxf(fmaxf(sc[1][qi][0], sc[1][qi][1]), fmaxf(sc[1][qi][2], sc[1][qi][3]));
                float t2 = fmaxf(fmaxf(sc[2][qi][0], sc[2][qi][1]), fmaxf(sc[2][qi][2], sc[2][qi][3]));
                float t3 = fmaxf(fmaxf(sc[3][qi][0], sc[3][qi][1]), fmaxf(sc[3][qi][2], sc[3][qi][3]));
                float tm = fmaxf(fmaxf(t0,t1), fmaxf(t2,t3));
                tm = fmaxf(tm, __shfl_xor(tm,16));
                tm = fmaxf(tm, __shfl_xor(tm,32));
                pmax[qi] = tm;
            }
            bool need = (pmax[0] > mrow[0]+8.0f) || (pmax[1] > mrow[1]+8.0f);
            if (__any(need)){
                float aq[2];
                #pragma unroll
                for (int qi=0;qi<2;++qi){
                    float mnew = fmaxf(mrow[qi], pmax[qi]);
                    aq[qi] = __builtin_amdgcn_exp2f(mrow[qi] - mnew);
                    mrow[qi] = mnew;
                    lrow[qi] *= aq[qi];
                }
                float am[2][4];
                #pragma unroll
                for (int mf=0;mf<2;++mf)
                    #pragma unroll
                    for (int j=0;j<4;++j) am[mf][j] = __shfl(aq[mf], lg*4+j);
                #pragma unroll
                for (int mf=0;mf<2;++mf)
                    #pragma unroll
                    for (int nf=0;nf<4;++nf)
                        #pragma unroll
                        for (int j=0;j<4;++j) oacc[mf][nf][j] *= am[mf][j];
            }
            #pragma unroll
            for (int qi=0;qi<2;++qi){
                float m = mrow[qi];
                float rs = 0.f;
                #pragma unroll
                for (int kf=0;kf<4;++kf)
                    #pragma unroll
                    for (int j=0;j<4;++j){
                        float e = __builtin_amdgcn_exp2f(sc[kf][qi][j] - m);
                        sc[kf][qi][j] = e;
                        rs += e;
                    }
                rs += __shfl_xor(rs,16);
                rs += __shfl_xor(rs,32);
                lrow[qi] += rs;
            }
            #pragma unroll
            for (int kf=0;kf<4;++kf)
                #pragma unroll
                for (int qi=0;qi<2;++qi){
                    u16x4 pk;
                    pk.x = f2h_bits(sc[kf][qi][0]);
                    pk.y = f2h_bits(sc[kf][qi][1]);
                    pk.z = f2h_bits(sc[kf][qi][2]);
                    pk.w = f2h_bits(sc[kf][qi][3]);
                    *reinterpret_cast<u16x4*>(&plds[w][qi*16+lr][kf*16+lg*4]) = pk;
                }
            half8 pa[2][2];
            #pragma unroll
            for (int mf=0;mf<2;++mf)
                #pragma unroll
                for (int kh=0;kh<2;++kh)
                    pa[mf][kh] = *reinterpret_cast<const half8*>(&plds[w][mf*16+lr][kh*32 + lg*8]);
            __builtin_amdgcn_s_setprio(1);
            #pragma unroll
            for (int mf=0;mf<2;++mf)
                #pragma unroll
                for (int nf=0;nf<4;++nf)
                    #pragma unroll
                    for (int kh=0;kh<2;++kh)
                        oacc[mf][nf] = __builtin_amdgcn_mfma_f32_16x16x32_f16(pa[mf][kh], vf[nf][kh], oacc[mf][nf], 0,0,0);
            __builtin_amdgcn_s_setprio(0);
        }
        __syncthreads();
    }

    float linv[2][4];
    #pragma unroll
    for (int mf=0;mf<2;++mf)
        #pragma unroll
        for (int j=0;j<4;++j) linv[mf][j] = 1.0f/__shfl(lrow[mf], lg*4+j);
    if (!split){
        #pragma unroll
        for (int mf=0;mf<2;++mf)
            #pragma unroll
            for (int nf=0;nf<4;++nf)
                #pragma unroll
                for (int j=0;j<4;++j)
                    Mg[(size_t)(b*S_LEN + q0w + mf*16 + lg*4 + j)*D_MODEL + h*HDIM + nf*16 + lr]
                        = f2h_bits(oacc[mf][nf][j]*linv[mf][j]);
    } else {
        #pragma unroll
        for (int mf=0;mf<2;++mf)
            #pragma unroll
            for (int nf=0;nf<4;++nf)
                #pragma unroll
                for (int j=0;j<4;++j)
                    On[pid*8192 + (w*32 + mf*16 + lg*4 + j)*64 + nf*16 + lr]
                        = f2h_bits(oacc[mf][nf][j]*linv[mf][j]);
        if (lg == 0){
            #pragma unroll
            for (int qi=0;qi<2;++qi){
                Ml[pid*128 + w*32 + qi*16 + lr] = mrow[qi];
                Ll[pid*128 + w*32 + qi*16 + lr] = lrow[qi];
            }
        }
        // ---- second-finisher merge (release: fence before atomic; acquire: fence after) ----
        __threadfence();
        __syncthreads();
        if (t == 0) oldv = atomicAdd(&flags[fidx], 1u);
        __syncthreads();
        if (oldv == 1u){
            __threadfence();
            int pid0 = fidx*2, pid1 = pid0 + 1;
            #pragma unroll
            for (int it=0; it<8; ++it){
                int idx = it*256 + t;
                int r  = idx >> 4;
                int cc = (idx & 15)*4;
                float m1 = Ml[pid0*128 + r], m2 = Ml[pid1*128 + r];
                float l1 = Ll[pid0*128 + r], l2 = Ll[pid1*128 + r];
                float M  = fmaxf(m1, m2);
                float w1 = l1*__builtin_amdgcn_exp2f(m1 - M);
                float w2 = l2*__builtin_amdgcn_exp2f(m2 - M);
                float inv = 1.0f/(w1 + w2);
                u16x4 o1 = *reinterpret_cast<const u16x4*>(On + (size_t)pid0*8192 + r*64 + cc);
                u16x4 o2 = *reinterpret_cast<const u16x4*>(On + (size_t)pid1*8192 + r*64 + cc);
                u16x4 o;
                #pragma unroll
                for (int j=0;j<4;++j)
                    o[j] = f2h_bits((w1*h2f_bits(o1[j]) + w2*h2f_bits(o2[j]))*inv);
                *reinterpret_cast<u16x4*>(Mg + (size_t)(b*S_LEN + qb*128 + r)*D_MODEL + h*HDIM + cc) = o;
            }
        }
    }
}

extern "C" void kernel_launch(void* const* d_in, const int* in_sizes, int n_in,
                              void* d_out, int out_size, void* d_ws, size_t ws_size,
                              hipStream_t stream) {
    const float* x    = (const float*)d_in[0];
    const float* wqkv = (const float*)d_in[1];
    const float* wout = (const float*)d_in[2];
    float* out = (float*)d_out;
    char* ws = (char*)d_ws;

    const size_t MB = 1u<<20;
    u16* xh      = (u16*)(ws + 0*MB);
    u16* wqkvT   = (u16*)(ws + 8*MB);
    u16* woutT   = (u16*)(ws + 14*MB);
    u16* Qh      = (u16*)(ws + 16*MB);
    u16* Kh      = (u16*)(ws + 24*MB);
    u16* Vt      = (u16*)(ws + 32*MB);
    u16* Mg      = (u16*)(ws + 40*MB);
    u16* On      = (u16*)(ws + 48*MB);       // [512][128][64] fp16 normalized O partials (8MB)
    float* Ml    = (float*)(ws + 56*MB);     // [512][128] f32 (256KB)
    float* Ll    = (float*)(ws + 56*MB + 256*1024);
    unsigned* fl = (unsigned*)(ws + 56*MB + 512*1024);  // 256 merge flags (zeroed by k_cvt)

    k_cvt        <<<8193, 256, 0, stream>>>(x, xh, wqkv, wqkvT, wout, woutT, fl);
    k_gemm<1,128><<<768, 256, 0, stream>>>(xh, wqkvT, nullptr, Qh, Kh, Vt);
    k_attn       <<<768, 256, 0, stream>>>(Qh, Kh, Vt, Mg, On, Ml, Ll, fl);
    k_gemm<0,64> <<<512, 256, 0, stream>>>(Mg, woutT, out, nullptr, nullptr, nullptr);
}

// Round 24
// 110.463 us; speedup vs baseline: 1.7953x; 1.7953x over previous
//
#include <hip/hip_runtime.h>
#include <stdint.h>

using u16 = unsigned short;
typedef __attribute__((ext_vector_type(8))) _Float16 half8;
typedef __attribute__((ext_vector_type(4))) float f32x4;
typedef __attribute__((ext_vector_type(4))) unsigned short u16x4;

#define S_LEN 2048
#define D_MODEL 1024
#define NHEAD 16
#define HDIM 64

__device__ __forceinline__ u16 f2h_bits(float f){
    _Float16 h = (_Float16)f;
    return __builtin_bit_cast(u16, h);
}
__device__ __forceinline__ float h2f_bits(u16 v){
    return (float)__builtin_bit_cast(_Float16, v);
}

typedef __attribute__((address_space(1))) void gvoid;
typedef __attribute__((address_space(3))) void lvoid;
__device__ __forceinline__ void gload_lds16(const u16* g, u16* l){
    __builtin_amdgcn_global_load_lds((gvoid*)(uintptr_t)g, (lvoid*)l, 16, 0, 0);
}

// ---------- fused converts: x fp32->fp16 (blocks 0..4095) + both weight transposes ----------
__global__ __launch_bounds__(256) void k_cvt(const float* __restrict__ x, u16* __restrict__ xh,
                                             const float* __restrict__ W0, u16* __restrict__ T0,
                                             const float* __restrict__ W1, u16* __restrict__ T1){
    __shared__ float tt[32][33];
    int blk = blockIdx.x;
    if (blk < 4096){
        int i = blk*256 + threadIdx.x;
        float4 v = reinterpret_cast<const float4*>(x)[i];
        u16x4 o;
        o.x = f2h_bits(v.x); o.y = f2h_bits(v.y); o.z = f2h_bits(v.z); o.w = f2h_bits(v.w);
        reinterpret_cast<u16x4*>(xh)[i] = o;
        return;
    }
    int wi = blk - 4096;
    int bx = wi & 127, ky = wi >> 7;
    const float* W; u16* WT; int N, n0;
    if (bx < 96){ W = W0; WT = T0; N = 3072; n0 = bx*32; }
    else        { W = W1; WT = T1; N = 1024; n0 = (bx-96)*32; }
    int k0 = ky*32;
    int tx = threadIdx.x & 31, ty = threadIdx.x >> 5;
    #pragma unroll
    for (int i=0;i<4;++i) tt[ty+8*i][tx] = W[(size_t)(k0+ty+8*i)*N + n0+tx];
    __syncthreads();
    #pragma unroll
    for (int i=0;i<4;++i) WT[(size_t)(n0+ty+8*i)*1024 + k0+tx] = f2h_bits(tt[tx][ty+8*i]);
}

// ---------- GEMM: 128xBN block tile, BK=32, dbuf LDS, ONE barrier per K-step ----------
// BN = per-BLOCK N width; 2 waves span N -> per-wave NF = BN/32 fragments.
// BN=128: QKV (768 blocks = 3/CU). BN=64: out-proj (512 blocks = 2/CU).
template<int EPI, int BN>
__global__ __launch_bounds__(256) void k_gemm(const u16* __restrict__ A, const u16* __restrict__ BT,
                                              float* __restrict__ Cf, u16* __restrict__ Qh,
                                              u16* __restrict__ Kh, u16* __restrict__ Vt){
    constexpr int Kd = 1024;
    constexpr int NF = BN/32;                // per-wave n fragment count
    __shared__ u16 As[2*128*32];
    __shared__ u16 Bs[2*128*32];
    int nwg = gridDim.x;
    int cpx = nwg >> 3;
    int wg  = ((int)blockIdx.x & 7)*cpx + ((int)blockIdx.x >> 3);   // XCD-chunked (bijective: nwg%8==0)
    int tm = wg & 31, tn = wg >> 5;                                 // m-fastest within chunk
    int t = threadIdx.x;
    int w = t >> 6, lane = t & 63;
    int lr = lane & 15, lg = lane >> 4;
    int wm = (w>>1)*64, wn = (w&1)*(BN/2);
    int m0 = tm*128 + wm, n0 = tn*BN + wn;

    const u16* aG = A  + (size_t)(tm*128 + (t>>2))*Kd + (t&3)*8;
    const u16* bG = BT + (size_t)(tn*BN + (t>>2))*Kd + (t&3)*8;   // BN=64: rows 0..63 = full tile
    u16* aL = As + (t>>2)*32 + (t&3)*8;
    u16* bL = Bs + (t>>2)*32 + (t&3)*8;

    auto stage = [&](int buf, int kk){
        gload_lds16(aG + kk, aL + buf*4096);
        gload_lds16(aG + kk + (size_t)64*Kd, aL + buf*4096 + 64*32);
        gload_lds16(bG + kk, bL + buf*4096);
        if (BN == 128) gload_lds16(bG + kk + (size_t)64*Kd, bL + buf*4096 + 64*32);
    };

    f32x4 acc[4][NF];
    #pragma unroll
    for (int i=0;i<4;++i)
        #pragma unroll
        for (int j=0;j<NF;++j) acc[i][j] = (f32x4){0.f,0.f,0.f,0.f};

    stage(0, 0);
    __syncthreads();
    for (int kk=0; kk<Kd; kk+=32){
        int cur = (kk>>5) & 1;
        if (kk+32 < Kd) stage(cur^1, kk+32);

        half8 av[4], bv[NF];
        #pragma unroll
        for (int mf=0;mf<4;++mf) av[mf] = *reinterpret_cast<const half8*>(&As[cur*4096 + (wm+mf*16+lr)*32 + lg*8]);
        #pragma unroll
        for (int nf=0;nf<NF;++nf) bv[nf] = *reinterpret_cast<const half8*>(&Bs[cur*4096 + (wn+nf*16+lr)*32 + lg*8]);
        __builtin_amdgcn_s_setprio(1);
        #pragma unroll
        for (int mf=0;mf<4;++mf)
            #pragma unroll
            for (int nf=0;nf<NF;++nf)
                acc[mf][nf] = __builtin_amdgcn_mfma_f32_16x16x32_f16(av[mf], bv[nf], acc[mf][nf], 0,0,0);
        __builtin_amdgcn_s_setprio(0);
        __syncthreads();
    }

    if (EPI == 0){
        #pragma unroll
        for (int mf=0;mf<4;++mf)
            #pragma unroll
            for (int nf=0;nf<NF;++nf)
                #pragma unroll
                for (int j=0;j<4;++j)
                    Cf[(size_t)(m0+mf*16+lg*4+j)*D_MODEL + n0+nf*16+lr] = acc[mf][nf][j];
    } else {
        #pragma unroll
        for (int mf=0;mf<4;++mf){
            int r0 = m0 + mf*16 + lg*4;
            int b  = r0 >> 11, s = r0 & 2047;
            #pragma unroll
            for (int nf=0;nf<NF;++nf){
                int col = n0 + nf*16 + lr;
                int which = col >> 10;
                int d  = col & 1023;
                int h  = d >> 6, di = d & 63;
                int bh = b*NHEAD + h;
                if (which == 2){
                    u16x4 pv;
                    pv.x = f2h_bits(acc[mf][nf][0]);
                    pv.y = f2h_bits(acc[mf][nf][1]);
                    pv.z = f2h_bits(acc[mf][nf][2]);
                    pv.w = f2h_bits(acc[mf][nf][3]);
                    *reinterpret_cast<u16x4*>(Vt + ((size_t)bh*HDIM + di)*S_LEN + s) = pv;
                } else {
                    u16* dst = (which==0 ? Qh : Kh) + ((size_t)bh*S_LEN + s)*HDIM + di;
                    #pragma unroll
                    for (int j=0;j<4;++j) dst[(size_t)j*HDIM] = f2h_bits(acc[mf][nf][j]);
                }
            }
        }
    }
}

// ---------- flash attention (best build, verbatim): K+V LDS-staged, dbuf, 1 barrier ----------
__global__ __launch_bounds__(256,3) void k_attn(const u16* __restrict__ Q, const u16* __restrict__ K,
                                                const u16* __restrict__ Vt, u16* __restrict__ Mg,
                                                u16* __restrict__ On, float* __restrict__ Ml,
                                                float* __restrict__ Ll){
    __shared__ u16 Kl[2*64*64];
    __shared__ u16 Vl[2*64*64];
    __shared__ u16 plds[4][32][72];
    int t = threadIdx.x;
    int w = t >> 6, lane = t & 63;
    int lr = lane & 15, lg = lane >> 4;
    int blk = blockIdx.x;
    int bh  = blk & 31;                      // XCD = bh%8: K/V L2-pinned
    int p   = blk >> 5;                      // 0..23
    int qb, ktLo, ktHi, part; bool split;
    if (p < 8)      { qb = p;    ktLo = 0;      ktHi = 2*p+2;   split = false; part = 0; }
    else if (p < 16){ qb = 23-p; ktLo = 0;      ktHi = qb+1;    split = true;  part = 0; }
    else            { qb = 31-p; ktLo = qb+1;   ktHi = 2*qb+2;  split = true;  part = 1; }
    int q0w = qb*128 + w*32;
    int b = bh >> 4, h = bh & 15;
    int pid = split ? ((bh<<3) + (qb-8))*2 + part : 0;
    const u16* Qp = Q  + (size_t)bh*S_LEN*HDIM;
    const u16* Kp = K  + (size_t)bh*S_LEN*HDIM;
    const u16* Vp = Vt + (size_t)bh*HDIM*S_LEN;

    int c0 = t, c1 = t + 256;
    int r0 = c0 >> 3, s0 = 8*((c0 & 7) ^ (r0 & 7));
    int r1 = c1 >> 3, s1 = 8*((c1 & 7) ^ (r1 & 7));
    const u16* Ks0 = Kp + (size_t)r0*HDIM + s0;
    const u16* Ks1 = Kp + (size_t)r1*HDIM + s1;
    const u16* Vs0 = Vp + (size_t)r0*S_LEN + s0;
    const u16* Vs1 = Vp + (size_t)r1*S_LEN + s1;
    u16* Kd0 = Kl + c0*8; u16* Kd1 = Kl + c1*8;
    u16* Vd0 = Vl + c0*8; u16* Vd1 = Vl + c1*8;

    auto stageKV = [&](int buf, int kt){
        int kbase = kt*64;
        gload_lds16(Ks0 + (size_t)kbase*HDIM, Kd0 + buf*4096);
        gload_lds16(Ks1 + (size_t)kbase*HDIM, Kd1 + buf*4096);
        gload_lds16(Vs0 + kbase, Vd0 + buf*4096);
        gload_lds16(Vs1 + kbase, Vd1 + buf*4096);
    };

    half8 qf[2][2];
    #pragma unroll
    for (int qi=0;qi<2;++qi)
        #pragma unroll
        for (int ks=0;ks<2;++ks){
            half8 v = *reinterpret_cast<const half8*>(Qp + (size_t)(q0w+qi*16+lr)*HDIM + ks*32 + lg*8);
            #pragma unroll
            for (int j=0;j<8;++j) v[j] = v[j] * (_Float16)1.44269504f;
            qf[qi][ks] = v;
        }

    f32x4 oacc[2][4];
    float mrow[2], lrow[2];
    #pragma unroll
    for (int mf=0;mf<2;++mf){
        #pragma unroll
        for (int nf=0;nf<4;++nf) oacc[mf][nf] = (f32x4){0.f,0.f,0.f,0.f};
        mrow[mf] = -1e30f; lrow[mf] = 0.f;
    }

    int lastkt = (q0w + 31) >> 6;
    int swz = (lr & 7)*8;
    int nT = ktHi - ktLo;

    stageKV(0, ktLo);
    __syncthreads();
    for (int i=0; i<nT; ++i){
        int kt = ktLo + i;
        int cur = i & 1;
        if (i+1 < nT) stageKV(cur^1, kt+1);

        if (kt <= lastkt){
            const u16* Kb = Kl + cur*4096;
            const u16* Vb = Vl + cur*4096;
            int kbase = kt*64;
            half8 kfr[4][2];
            #pragma unroll
            for (int kf=0;kf<4;++kf)
                #pragma unroll
                for (int ks=0;ks<2;++ks)
                    kfr[kf][ks] = *reinterpret_cast<const half8*>(Kb + (kf*16+lr)*64 + ((ks*32 + lg*8) ^ swz));
            f32x4 sc[4][2];
            #pragma unroll
            for (int kf=0;kf<4;++kf)
                #pragma unroll
                for (int qi=0;qi<2;++qi) sc[kf][qi] = (f32x4){0.f,0.f,0.f,0.f};
            __builtin_amdgcn_s_setprio(1);
            #pragma unroll
            for (int kf=0;kf<4;++kf)
                #pragma unroll
                for (int qi=0;qi<2;++qi)
                    #pragma unroll
                    for (int ks=0;ks<2;++ks)
                        sc[kf][qi] = __builtin_amdgcn_mfma_f32_16x16x32_f16(kfr[kf][ks], qf[qi][ks], sc[kf][qi], 0,0,0);
            __builtin_amdgcn_s_setprio(0);

            half8 vf[4][2];
            #pragma unroll
            for (int nf=0;nf<4;++nf)
                #pragma unroll
                for (int kh=0;kh<2;++kh)
                    vf[nf][kh] = *reinterpret_cast<const half8*>(Vb + (nf*16+lr)*64 + ((kh*32 + lg*8) ^ swz));

            if (kt == lastkt){
                #pragma unroll
                for (int kf=0;kf<4;++kf)
                    #pragma unroll
                    for (int qi=0;qi<2;++qi)
                        #pragma unroll
                        for (int j=0;j<4;++j)
                            if (kbase+kf*16+lg*4+j > q0w+qi*16+lr) sc[kf][qi][j] = -1e9f;
            }

            float pmax[2];
            #pragma unroll
            for (int qi=0;qi<2;++qi){
                float t0 = fmaxf(fmaxf(sc[0][qi][0], sc[0][qi][1]), fmaxf(sc[0][qi][2], sc[0][qi][3]));
                float t1 = fmaxf(fmaxf(sc[1][qi][0], sc[1][qi][1]), fmaxf(sc[1][qi][2], sc[1][qi][3]));
                float t2 = fmaxf(fmaxf(sc[2][qi][0], sc[2][qi][1]), fmaxf(sc[2][qi][2], sc[2][qi][3]));
                float t3 = fmaxf(fmaxf(sc[3][qi][0], sc[3][qi][1]), fmaxf(sc[3][qi][2], sc[3][qi][3]));
                float tm = fmaxf(fmaxf(t0,t1), fmaxf(t2,t3));
                tm = fmaxf(tm, __shfl_xor(tm,16));
                tm = fmaxf(tm, __shfl_xor(tm,32));
                pmax[qi] = tm;
            }
            bool need = (pmax[0] > mrow[0]+8.0f) || (pmax[1] > mrow[1]+8.0f);
            if (__any(need)){
                float aq[2];
                #pragma unroll
                for (int qi=0;qi<2;++qi){
                    float mnew = fmaxf(mrow[qi], pmax[qi]);
                    aq[qi] = __builtin_amdgcn_exp2f(mrow[qi] - mnew);
                    mrow[qi] = mnew;
                    lrow[qi] *= aq[qi];
                }
                float am[2][4];
                #pragma unroll
                for (int mf=0;mf<2;++mf)
                    #pragma unroll
                    for (int j=0;j<4;++j) am[mf][j] = __shfl(aq[mf], lg*4+j);
                #pragma unroll
                for (int mf=0;mf<2;++mf)
                    #pragma unroll
                    for (int nf=0;nf<4;++nf)
                        #pragma unroll
                        for (int j=0;j<4;++j) oacc[mf][nf][j] *= am[mf][j];
            }
            #pragma unroll
            for (int qi=0;qi<2;++qi){
                float m = mrow[qi];
                float rs = 0.f;
                #pragma unroll
                for (int kf=0;kf<4;++kf)
                    #pragma unroll
                    for (int j=0;j<4;++j){
                        float e = __builtin_amdgcn_exp2f(sc[kf][qi][j] - m);
                        sc[kf][qi][j] = e;
                        rs += e;
                    }
                rs += __shfl_xor(rs,16);
                rs += __shfl_xor(rs,32);
                lrow[qi] += rs;
            }
            #pragma unroll
            for (int kf=0;kf<4;++kf)
                #pragma unroll
                for (int qi=0;qi<2;++qi){
                    u16x4 pk;
                    pk.x = f2h_bits(sc[kf][qi][0]);
                    pk.y = f2h_bits(sc[kf][qi][1]);
                    pk.z = f2h_bits(sc[kf][qi][2]);
                    pk.w = f2h_bits(sc[kf][qi][3]);
                    *reinterpret_cast<u16x4*>(&plds[w][qi*16+lr][kf*16+lg*4]) = pk;
                }
            half8 pa[2][2];
            #pragma unroll
            for (int mf=0;mf<2;++mf)
                #pragma unroll
                for (int kh=0;kh<2;++kh)
                    pa[mf][kh] = *reinterpret_cast<const half8*>(&plds[w][mf*16+lr][kh*32 + lg*8]);
            __builtin_amdgcn_s_setprio(1);
            #pragma unroll
            for (int mf=0;mf<2;++mf)
                #pragma unroll
                for (int nf=0;nf<4;++nf)
                    #pragma unroll
                    for (int kh=0;kh<2;++kh)
                        oacc[mf][nf] = __builtin_amdgcn_mfma_f32_16x16x32_f16(pa[mf][kh], vf[nf][kh], oacc[mf][nf], 0,0,0);
            __builtin_amdgcn_s_setprio(0);
        }
        __syncthreads();
    }

    float linv[2][4];
    #pragma unroll
    for (int mf=0;mf<2;++mf)
        #pragma unroll
        for (int j=0;j<4;++j) linv[mf][j] = 1.0f/__shfl(lrow[mf], lg*4+j);
    if (!split){
        #pragma unroll
        for (int mf=0;mf<2;++mf)
            #pragma unroll
            for (int nf=0;nf<4;++nf)
                #pragma unroll
                for (int j=0;j<4;++j)
                    Mg[(size_t)(b*S_LEN + q0w + mf*16 + lg*4 + j)*D_MODEL + h*HDIM + nf*16 + lr]
                        = f2h_bits(oacc[mf][nf][j]*linv[mf][j]);
    } else {
        #pragma unroll
        for (int mf=0;mf<2;++mf)
            #pragma unroll
            for (int nf=0;nf<4;++nf)
                #pragma unroll
                for (int j=0;j<4;++j)
                    On[pid*8192 + (w*32 + mf*16 + lg*4 + j)*64 + nf*16 + lr]
                        = f2h_bits(oacc[mf][nf][j]*linv[mf][j]);
        if (lg == 0){
            #pragma unroll
            for (int qi=0;qi<2;++qi){
                Ml[pid*128 + w*32 + qi*16 + lr] = mrow[qi];
                Ll[pid*128 + w*32 + qi*16 + lr] = lrow[qi];
            }
        }
    }
}

// ---------- partial merge (flat streaming, verbatim): 2048 blocks ----------
__global__ __launch_bounds__(256) void k_comb(const u16* __restrict__ On, const float* __restrict__ Ml,
                                              const float* __restrict__ Ll, u16* __restrict__ Mg){
    int blk = blockIdx.x;
    int bh = blk & 31;
    int q8 = (blk >> 5) & 7;                 // qb = 8+q8
    int rq = blk >> 8;                       // 0..7 row-group
    int qb = 8 + q8;
    int b = bh >> 4, h = bh & 15;
    int t = threadIdx.x;
    int r  = rq*16 + (t >> 4);
    int cc = (t & 15) * 4;
    int pid0 = ((bh<<3) + q8)*2, pid1 = pid0 + 1;
    float m1 = Ml[pid0*128 + r], m2 = Ml[pid1*128 + r];
    float l1 = Ll[pid0*128 + r], l2 = Ll[pid1*128 + r];
    float M  = fmaxf(m1, m2);
    float w1 = l1*__builtin_amdgcn_exp2f(m1 - M);
    float w2 = l2*__builtin_amdgcn_exp2f(m2 - M);
    float inv = 1.0f/(w1 + w2);
    u16x4 o1 = *reinterpret_cast<const u16x4*>(On + (size_t)pid0*8192 + r*64 + cc);
    u16x4 o2 = *reinterpret_cast<const u16x4*>(On + (size_t)pid1*8192 + r*64 + cc);
    u16x4 o;
    #pragma unroll
    for (int j=0;j<4;++j)
        o[j] = f2h_bits((w1*h2f_bits(o1[j]) + w2*h2f_bits(o2[j]))*inv);
    *reinterpret_cast<u16x4*>(Mg + (size_t)(b*S_LEN + qb*128 + r)*D_MODEL + h*HDIM + cc) = o;
}

extern "C" void kernel_launch(void* const* d_in, const int* in_sizes, int n_in,
                              void* d_out, int out_size, void* d_ws, size_t ws_size,
                              hipStream_t stream) {
    const float* x    = (const float*)d_in[0];
    const float* wqkv = (const float*)d_in[1];
    const float* wout = (const float*)d_in[2];
    float* out = (float*)d_out;
    char* ws = (char*)d_ws;

    const size_t MB = 1u<<20;
    u16* xh     = (u16*)(ws + 0*MB);
    u16* wqkvT  = (u16*)(ws + 8*MB);
    u16* woutT  = (u16*)(ws + 14*MB);
    u16* Qh     = (u16*)(ws + 16*MB);
    u16* Kh     = (u16*)(ws + 24*MB);
    u16* Vt     = (u16*)(ws + 32*MB);
    u16* Mg     = (u16*)(ws + 40*MB);
    u16* On     = (u16*)(ws + 48*MB);        // [512][128][64] fp16 normalized O partials (8MB)
    float* Ml   = (float*)(ws + 56*MB);      // [512][128] f32 (256KB)
    float* Ll   = (float*)(ws + 56*MB + 256*1024);

    k_cvt        <<<8192, 256, 0, stream>>>(x, xh, wqkv, wqkvT, wout, woutT);
    k_gemm<1,128><<<768, 256, 0, stream>>>(xh, wqkvT, nullptr, Qh, Kh, Vt);
    k_attn       <<<768, 256, 0, stream>>>(Qh, Kh, Vt, Mg, On, Ml, Ll);
    k_comb       <<<2048, 256, 0, stream>>>(On, Ml, Ll, Mg);
    k_gemm<0,64> <<<512, 256, 0, stream>>>(Mg, woutT, out, nullptr, nullptr, nullptr);
}